// Round 2
// baseline (3811.918 us; speedup 1.0000x reference)
//
#include <hip/hip_runtime.h>
#include <math.h>

// ---------------------------------------------------------------------------
// MemoryLayerAttention: 8-step recurrent transformer cell.
//   N=128 sequences, L=257 rows, E=32, CH=4 heads, KD=32, FF=128, R=256, C=32.
// Per step (graph-captured):
//   k_aug  : em = mem@W_me, ei = inp@W_in, z = concat + PE      (4-way e-split)
//   k_proj : K,V,Q(n,h,l,32) -> global scratch (Q pre-scaled)
//   k_attn : one block per (n,h); one lane per query row; K/V rows read with
//            wave-uniform addresses (compiler -> s_load, SGPR fma operands);
//            no LDS, no barriers. Chunk-8 online softmax.
//   k_ffln : att=LN(mha+z); nf=LN(relu(att@Wf1)@Wf2+att); out at t==7
//   k_mem  : mi = nf[1:]@W_mi; double-sigmoid gated memory      (4-way c-split)
// ---------------------------------------------------------------------------

#define L_SEQ 257
#define SCALE 0.17677669529663689f   // 1/sqrt(32)

// ws layout (floats)
#define MEM_SZ  (128*256*32)
#define Z_SZ    (128*257*32)
#define HO_SZ   (128*4*257*32)
#define NF_SZ   (128*257*32)
#define PE_SZ   (L_SEQ*32)
#define QKV_SZ  (512*L_SEQ*32)

// ---------------------------------------------------------------------------
__global__ void k_init(float* __restrict__ mem) {
  const int i = blockIdx.x*256 + threadIdx.x;
  if (i < MEM_SZ) mem[i] = 1e-6f;
}

// PE computed in double to match numpy's float64 path; runs once per call.
__global__ void k_pe(float* __restrict__ pe) {
  const int i = blockIdx.x*256 + threadIdx.x;
  if (i >= L_SEQ*32) return;
  const int row = i >> 5, e = i & 31;
  const int k = e >> 1;
  const double p10 = pow(10000.0, (double)(2*k)/32.0);
  const double ang = (double)row / p10;
  pe[i] = (float)((e & 1) ? cos(ang) : sin(ang));
}

// ---------------------------------------------------------------------------
// grid (129, 4): blockIdx.y = e-quarter (uniform -> weight reads scalarized)
__global__ void k_aug(const float* __restrict__ queries, const float* __restrict__ values,
                      const float* __restrict__ W_in, const float* __restrict__ b_in,
                      const float* __restrict__ W_me, const float* __restrict__ b_me,
                      const float* __restrict__ mem, const float* __restrict__ pe,
                      float* __restrict__ z, int t) {
  const int gid = blockIdx.x*256 + threadIdx.x;
  if (gid >= 128*L_SEQ) return;
  const int e0 = blockIdx.y * 8;
  const int n = gid / L_SEQ, row = gid - n*L_SEQ;
  float acc[8];
  if (row == 0) {
    #pragma unroll
    for (int k = 0; k < 8; k++) acc[k] = b_in[e0+k];
    const float* q = queries + n*32;                       // (b*4+qi)*32 == n*32
    const float* v = values + (size_t)((n>>2)*8 + t)*32;
    for (int c = 0; c < 32; c++) {
      const float qc = q[c], vc = v[c];
      #pragma unroll
      for (int k = 0; k < 8; k++) acc[k] += qc*W_in[c*32+e0+k] + vc*W_in[(32+c)*32+e0+k];
    }
  } else {
    #pragma unroll
    for (int k = 0; k < 8; k++) acc[k] = b_me[e0+k];
    const float* mr = mem + ((size_t)n*256 + (row-1))*32;
    for (int c = 0; c < 32; c++) {
      const float mc = mr[c];
      #pragma unroll
      for (int k = 0; k < 8; k++) acc[k] += mc*W_me[c*32+e0+k];
    }
  }
  float* zr = z + (size_t)gid*32 + e0;
  const float* per = pe + row*32 + e0;
  #pragma unroll
  for (int k = 0; k < 8; k++) zr[k] = acc[k] + per[k];
}

// ---------------------------------------------------------------------------
// grid (512, 3): blockIdx.x = n*4+h, blockIdx.y = which (0:K 1:V 2:Q-scaled)
__global__ void k_proj(const float* __restrict__ z,
                       const float* __restrict__ Wq, const float* __restrict__ bq,
                       const float* __restrict__ Wk, const float* __restrict__ bk,
                       const float* __restrict__ Wv, const float* __restrict__ bv,
                       float* __restrict__ Kg, float* __restrict__ Vg,
                       float* __restrict__ Qg) {
  const int nh = blockIdx.x, which = blockIdx.y;
  const int n = nh >> 2, h = nh & 3;
  const float* W  = (which == 0) ? Wk : (which == 1) ? Wv : Wq;
  const float* bb = (which == 0) ? bk : (which == 1) ? bv : bq;
  float* out      = (which == 0) ? Kg : (which == 1) ? Vg : Qg;
  const float scale = (which == 2) ? SCALE : 1.0f;
  const float* zb = z + (size_t)n*L_SEQ*32;

  for (int r = threadIdx.x; r < L_SEQ; r += 256) {
    float acc[32];
    #pragma unroll
    for (int d = 0; d < 32; d++) acc[d] = bb[h*32+d];
    const float* zr = zb + r*32;
    for (int e = 0; e < 32; e++) {
      const float ze = zr[e];
      #pragma unroll
      for (int d = 0; d < 32; d++) acc[d] += ze * W[e*128 + h*32 + d];
    }
    float4* dst = (float4*)(out + ((size_t)nh*L_SEQ + r)*32);
    #pragma unroll
    for (int c = 0; c < 8; c++)
      dst[c] = make_float4(acc[4*c]*scale, acc[4*c+1]*scale, acc[4*c+2]*scale, acc[4*c+3]*scale);
  }
}

// ---------------------------------------------------------------------------
// One block per (n,h). Lane tid owns query row tid (rows 0..255); row 256 is
// handled cooperatively by wave (blockIdx&3). K/V rows are read at
// wave-uniform addresses from read-only global -> s_load -> SGPR fma operands.
__global__ void k_attn(const float* __restrict__ Qg, const float* __restrict__ Kg,
                       const float* __restrict__ Vg, const float* __restrict__ Wo,
                       float* __restrict__ headout) {
  const int nh = blockIdx.x;
  const int h = nh & 3;
  const int tid = threadIdx.x;
  const float* Kb = Kg + (size_t)nh*L_SEQ*32;
  const float* Vb = Vg + (size_t)nh*L_SEQ*32;
  const float* Qb = Qg + (size_t)nh*L_SEQ*32;
  const float* wo = Wo + h*1024;
  float* hob = headout + (size_t)nh*L_SEQ*32;

  // ---- per-lane query row ----
  float q[32];
  {
    const float4* qr = (const float4*)(Qb + (size_t)tid*32);
    #pragma unroll
    for (int c = 0; c < 8; c++) {
      const float4 t4 = qr[c];
      q[4*c] = t4.x; q[4*c+1] = t4.y; q[4*c+2] = t4.z; q[4*c+3] = t4.w;
    }
  }
  float o[32];
  #pragma unroll
  for (int d = 0; d < 32; d++) o[d] = 0.f;
  float m = -1e30f, sum = 0.f;

  #pragma unroll 1
  for (int ch = 0; ch < 32; ch++) {
    float sc[8];
    // phase 1: scores for 8 keys (K rows wave-uniform -> SGPRs)
    #pragma unroll
    for (int jj = 0; jj < 8; jj++) {
      const int l = ch*8 + jj;
      const float4* kr = (const float4*)(Kb + l*32);
      float s0 = 0.f, s1 = 0.f, s2 = 0.f, s3 = 0.f;
      #pragma unroll
      for (int c = 0; c < 8; c++) {
        const float4 kc = kr[c];
        s0 += q[4*c]*kc.x;   s1 += q[4*c+1]*kc.y;
        s2 += q[4*c+2]*kc.z; s3 += q[4*c+3]*kc.w;
      }
      sc[jj] = (s0 + s1) + (s2 + s3);
    }
    // chunk max + (exact) skip of rescale when no lane improves its max
    float cm = sc[0];
    #pragma unroll
    for (int jj = 1; jj < 8; jj++) cm = fmaxf(cm, sc[jj]);
    if (!__all(cm <= m)) {
      const float nm = fmaxf(m, cm);
      const float e0 = __expf(m - nm);
      sum *= e0;
      #pragma unroll
      for (int d = 0; d < 32; d++) o[d] *= e0;
      m = nm;
    }
    // phase 2: PV (V rows wave-uniform -> SGPRs)
    #pragma unroll
    for (int jj = 0; jj < 8; jj++) {
      const int l = ch*8 + jj;
      const float p = __expf(sc[jj] - m);
      sum += p;
      const float4* vr = (const float4*)(Vb + l*32);
      #pragma unroll
      for (int c = 0; c < 8; c++) {
        const float4 vc = vr[c];
        o[4*c]   += p*vc.x; o[4*c+1] += p*vc.y;
        o[4*c+2] += p*vc.z; o[4*c+3] += p*vc.w;
      }
    }
  }
  // ---- key 256 ----
  {
    const float4* kr = (const float4*)(Kb + 256*32);
    float s0 = 0.f, s1 = 0.f, s2 = 0.f, s3 = 0.f;
    #pragma unroll
    for (int c = 0; c < 8; c++) {
      const float4 kc = kr[c];
      s0 += q[4*c]*kc.x;   s1 += q[4*c+1]*kc.y;
      s2 += q[4*c+2]*kc.z; s3 += q[4*c+3]*kc.w;
    }
    const float x = (s0 + s1) + (s2 + s3);
    const float nm = fmaxf(m, x);
    const float e0 = __expf(m - nm), p = __expf(x - nm);
    sum = sum*e0 + p;
    const float4* vr = (const float4*)(Vb + 256*32);
    #pragma unroll
    for (int c = 0; c < 8; c++) {
      const float4 vc = vr[c];
      o[4*c]   = o[4*c]*e0   + p*vc.x; o[4*c+1] = o[4*c+1]*e0 + p*vc.y;
      o[4*c+2] = o[4*c+2]*e0 + p*vc.z; o[4*c+3] = o[4*c+3]*e0 + p*vc.w;
    }
    m = nm;
  }
  // ---- output projection (Wo reads wave-uniform) ----
  {
    const float inv = 1.f/sum;
    float outv[32];
    #pragma unroll 4
    for (int d = 0; d < 32; d++) {
      float a = 0.f;
      #pragma unroll
      for (int kd = 0; kd < 32; kd++) a += o[kd]*wo[kd*32 + d];
      outv[d] = a*inv;
    }
    float4* dst = (float4*)(hob + (size_t)tid*32);
    #pragma unroll
    for (int c = 0; c < 8; c++)
      dst[c] = make_float4(outv[4*c], outv[4*c+1], outv[4*c+2], outv[4*c+3]);
  }
  // ---- query row 256: one (rotating) wave, lanes split keys, butterfly merge
  if ((tid >> 6) == (blockIdx.x & 3)) {
    const int lane = tid & 63;
    float q2[32];
    {
      const float4* qr = (const float4*)(Qb + 256*32);   // uniform
      #pragma unroll
      for (int c = 0; c < 8; c++) {
        const float4 t4 = qr[c];
        q2[4*c] = t4.x; q2[4*c+1] = t4.y; q2[4*c+2] = t4.z; q2[4*c+3] = t4.w;
      }
    }
    float m2 = -1e30f, s2 = 0.f, o2[32];
    #pragma unroll
    for (int d = 0; d < 32; d++) o2[d] = 0.f;
    for (int l = lane; l < L_SEQ; l += 64) {
      const float4* kr = (const float4*)(Kb + l*32);     // per-lane (vector)
      const float4* vr = (const float4*)(Vb + l*32);
      float s0 = 0.f, s1 = 0.f, s2p = 0.f, s3 = 0.f;
      #pragma unroll
      for (int c = 0; c < 8; c++) {
        const float4 kc = kr[c];
        s0 += q2[4*c]*kc.x;   s1 += q2[4*c+1]*kc.y;
        s2p += q2[4*c+2]*kc.z; s3 += q2[4*c+3]*kc.w;
      }
      const float x = (s0 + s1) + (s2p + s3);
      const float nm = fmaxf(m2, x);
      const float e0 = __expf(m2 - nm), p = __expf(x - nm);
      s2 = s2*e0 + p;
      #pragma unroll
      for (int c = 0; c < 8; c++) {
        const float4 vc = vr[c];
        o2[4*c]   = o2[4*c]*e0   + p*vc.x; o2[4*c+1] = o2[4*c+1]*e0 + p*vc.y;
        o2[4*c+2] = o2[4*c+2]*e0 + p*vc.z; o2[4*c+3] = o2[4*c+3]*e0 + p*vc.w;
      }
      m2 = nm;
    }
    #pragma unroll 1
    for (int off = 1; off < 64; off <<= 1) {
      const float om = __shfl_xor(m2, off);
      const float os = __shfl_xor(s2, off);
      const float nm = fmaxf(m2, om);
      const float me = __expf(m2 - nm), oe = __expf(om - nm);
      s2 = s2*me + os*oe;
      #pragma unroll
      for (int d = 0; d < 32; d++) o2[d] = o2[d]*me + __shfl_xor(o2[d], off)*oe;
      m2 = nm;
    }
    if (lane < 32) {
      const float inv = 1.f/s2;
      float a = 0.f;
      #pragma unroll
      for (int kd = 0; kd < 32; kd++) a += o2[kd]*wo[kd*32 + lane];
      hob[256*32 + lane] = a*inv;
    }
  }
}

// ---------------------------------------------------------------------------
// att = LN(sum_h headout + bo + z); nf = LN(relu(att@Wf1+b1)@Wf2+b2+att).
// 4 threads per row, each owns 32 of the 128 hidden units; shfl-merge partials.
__global__ void k_ffln(const float* __restrict__ headout, const float* __restrict__ z,
                       const float* __restrict__ bo,
                       const float* __restrict__ W_f1, const float* __restrict__ b_f1,
                       const float* __restrict__ W_f2, const float* __restrict__ b_f2,
                       const float* __restrict__ ln_g, const float* __restrict__ ln_b,
                       const float* __restrict__ W_out, const float* __restrict__ b_out,
                       float* __restrict__ nf, float* __restrict__ outp, int t) {
  const int gid = blockIdx.x*256 + threadIdx.x;   // exactly 128*257*4 threads
  const int rowid = gid >> 2, part = gid & 3;
  const int n = rowid / L_SEQ, row = rowid - n*L_SEQ;
  float att[32];
  const float* hob = headout + (size_t)n*4*L_SEQ*32 + (size_t)row*32;
  const float* zr = z + (size_t)rowid*32;
  #pragma unroll
  for (int e = 0; e < 32; e++)
    att[e] = bo[e] + zr[e] + hob[e] + hob[L_SEQ*32 + e]
           + hob[2*L_SEQ*32 + e] + hob[3*L_SEQ*32 + e];
  float mu = 0.f;
  #pragma unroll
  for (int e = 0; e < 32; e++) mu += att[e];
  mu *= (1.f/32.f);
  float var = 0.f;
  #pragma unroll
  for (int e = 0; e < 32; e++) { const float d = att[e]-mu; var += d*d; }
  var *= (1.f/32.f);
  float rstd = 1.f/sqrtf(var + 1e-6f);
  #pragma unroll
  for (int e = 0; e < 32; e++) att[e] = (att[e]-mu)*rstd*ln_g[e] + ln_b[e];

  float y[32];
  #pragma unroll
  for (int e = 0; e < 32; e++) y[e] = 0.f;
  for (int jj = 0; jj < 32; jj++) {
    const int j = part*32 + jj;
    float hv = b_f1[j];
    #pragma unroll
    for (int e = 0; e < 32; e++) hv += att[e]*W_f1[e*128 + j];
    hv = fmaxf(hv, 0.f);
    #pragma unroll
    for (int e = 0; e < 32; e++) y[e] += hv*W_f2[j*32 + e];
  }
  #pragma unroll
  for (int e = 0; e < 32; e++) y[e] += __shfl_xor(y[e], 1);
  #pragma unroll
  for (int e = 0; e < 32; e++) y[e] += __shfl_xor(y[e], 2);
  #pragma unroll
  for (int e = 0; e < 32; e++) y[e] += b_f2[e] + att[e];

  mu = 0.f;
  #pragma unroll
  for (int e = 0; e < 32; e++) mu += y[e];
  mu *= (1.f/32.f);
  var = 0.f;
  #pragma unroll
  for (int e = 0; e < 32; e++) { const float d = y[e]-mu; var += d*d; }
  var *= (1.f/32.f);
  rstd = 1.f/sqrtf(var + 1e-6f);
  float nfv[32];
  #pragma unroll
  for (int e = 0; e < 32; e++) nfv[e] = (y[e]-mu)*rstd*ln_g[e] + ln_b[e];

  float* nr = nf + (size_t)rowid*32;
  #pragma unroll
  for (int dd = 0; dd < 8; dd++) { const int e = part*8 + dd; nr[e] = nfv[e]; }

  if (t == 7 && row == 0 && part == 0) {
    float a = b_out[0];
    #pragma unroll
    for (int e = 0; e < 32; e++) a += nfv[e]*W_out[e];
    outp[n] = a;
  }
}

// ---------------------------------------------------------------------------
// grid (128, 4): blockIdx.y = c-quarter (uniform -> W_mi reads scalarized)
__global__ void k_mem(const float* __restrict__ nf, const float* __restrict__ W_mi,
                      const float* __restrict__ b_mi, float* __restrict__ mem) {
  const int rowid = blockIdx.x*256 + threadIdx.x;  // 0..32767
  const int cq = blockIdx.y;
  const int n = rowid >> 8, r = rowid & 255;
  const float* x = nf + ((size_t)n*L_SEQ + 1 + r)*32;
  float xr[32];
  #pragma unroll
  for (int e = 0; e < 32; e++) xr[e] = x[e];
  float mi0 = b_mi[0];
  #pragma unroll
  for (int e = 0; e < 32; e++) mi0 += xr[e]*W_mi[e*33];
  const float cs = 1.f/(1.f + expf(-mi0));
  const float ga = 1.f/(1.f + expf(cs));    // sigmoid(-cs)
  const float gb = 1.f/(1.f + expf(-cs));   // sigmoid(cs)
  float* mr = mem + (size_t)rowid*32;
  #pragma unroll 1
  for (int cc = 0; cc < 8; cc++) {
    const int c = cq*8 + cc;
    float mic = b_mi[1+c];
    #pragma unroll
    for (int e = 0; e < 32; e++) mic += xr[e]*W_mi[e*33 + 1 + c];
    mr[c] = ga*mr[c] + gb*mic;
  }
}

// ---------------------------------------------------------------------------
extern "C" void kernel_launch(void* const* d_in, const int* in_sizes, int n_in,
                              void* d_out, int out_size, void* d_ws, size_t ws_size,
                              hipStream_t stream) {
  const float* queries = (const float*)d_in[0];
  const float* values  = (const float*)d_in[1];
  const float* W_in = (const float*)d_in[2];   const float* b_in = (const float*)d_in[3];
  const float* W_me = (const float*)d_in[4];   const float* b_me = (const float*)d_in[5];
  const float* Wq   = (const float*)d_in[6];   const float* bq   = (const float*)d_in[7];
  const float* Wk   = (const float*)d_in[8];   const float* bk   = (const float*)d_in[9];
  const float* Wv   = (const float*)d_in[10];  const float* bv   = (const float*)d_in[11];
  const float* Wo   = (const float*)d_in[12];  const float* bo   = (const float*)d_in[13];
  const float* W_f1 = (const float*)d_in[14];  const float* b_f1 = (const float*)d_in[15];
  const float* W_f2 = (const float*)d_in[16];  const float* b_f2 = (const float*)d_in[17];
  const float* ln_g = (const float*)d_in[18];  const float* ln_b = (const float*)d_in[19];
  const float* W_out= (const float*)d_in[20];  const float* b_out= (const float*)d_in[21];
  const float* W_mi = (const float*)d_in[22];  const float* b_mi = (const float*)d_in[23];

  float* ws  = (float*)d_ws;
  float* mem = ws;                 // MEM_SZ
  float* z   = mem + MEM_SZ;       // Z_SZ
  float* ho  = z   + Z_SZ;         // HO_SZ
  float* nf  = ho  + HO_SZ;        // NF_SZ
  float* pe  = nf  + NF_SZ;        // PE_SZ
  float* Kg  = pe  + PE_SZ;        // QKV_SZ
  float* Vg  = Kg  + QKV_SZ;       // QKV_SZ
  float* Qg  = Vg  + QKV_SZ;       // QKV_SZ
  float* outp = (float*)d_out;     // 128 floats

  k_init<<<MEM_SZ/256, 256, 0, stream>>>(mem);
  k_pe<<<(L_SEQ*32 + 255)/256, 256, 0, stream>>>(pe);

  for (int t = 0; t < 8; t++) {
    k_aug <<<dim3(129, 4), 256, 0, stream>>>(queries, values, W_in, b_in,
                                             W_me, b_me, mem, pe, z, t);
    k_proj<<<dim3(512, 3), 256, 0, stream>>>(z, Wq, bq, Wk, bk, Wv, bv, Kg, Vg, Qg);
    k_attn<<<512, 256, 0, stream>>>(Qg, Kg, Vg, Wo, ho);
    k_ffln<<<(128*L_SEQ*4)/256, 256, 0, stream>>>(ho, z, bo, W_f1, b_f1, W_f2, b_f2,
                                                  ln_g, ln_b, W_out, b_out, nf, outp, t);
    k_mem <<<dim3(128, 4), 256, 0, stream>>>(nf, W_mi, b_mi, mem);
  }
}

// Round 3
// 3121.135 us; speedup vs baseline: 1.2213x; 1.2213x over previous
//
#include <hip/hip_runtime.h>
#include <math.h>

// ---------------------------------------------------------------------------
// MemoryLayerAttention: 8-step recurrent transformer cell.
//   N=128 sequences, L=257 rows, E=32, CH=4 heads, KD=32, FF=128, R=256, C=32.
// Per step (graph-captured):
//   k_proj   : K,V,Q(n,h,l,32) -> global scratch (Q pre-scaled)
//   k_attn   : one block per (n,h); one lane per query row; wave-uniform K/V
//   k_ffln   : att=LN(mha+z); nf=LN(relu(att@Wf1)@Wf2+att); out at t==7
//              (FF j-split is per-WAVE -> weight reads stay wave-uniform)
//   k_memaug : gated mem update fused with next step's z computation
// ---------------------------------------------------------------------------

#define L_SEQ 257
#define SCALE 0.17677669529663689f   // 1/sqrt(32)

// ws layout (floats)
#define MEM_SZ  (128*256*32)
#define Z_SZ    (128*257*32)
#define HO_SZ   (128*4*257*32)
#define NF_SZ   (128*257*32)
#define PE_SZ   (L_SEQ*32)
#define QKV_SZ  (512*L_SEQ*32)

// ---------------------------------------------------------------------------
__global__ void k_init(float* __restrict__ mem) {
  const int i = blockIdx.x*256 + threadIdx.x;
  if (i < MEM_SZ) mem[i] = 1e-6f;
}

// PE computed in double to match numpy's float64 path; runs once per call.
__global__ void k_pe(float* __restrict__ pe) {
  const int i = blockIdx.x*256 + threadIdx.x;
  if (i >= L_SEQ*32) return;
  const int row = i >> 5, e = i & 31;
  const int k = e >> 1;
  const double p10 = pow(10000.0, (double)(2*k)/32.0);
  const double ang = (double)row / p10;
  pe[i] = (float)((e & 1) ? cos(ang) : sin(ang));
}

// ---------------------------------------------------------------------------
// t=0 only. grid (129, 4): blockIdx.y = e-quarter (uniform weight reads)
__global__ __launch_bounds__(256, 2)
void k_aug(const float* __restrict__ queries, const float* __restrict__ values,
           const float* __restrict__ W_in, const float* __restrict__ b_in,
           const float* __restrict__ W_me, const float* __restrict__ b_me,
           const float* __restrict__ mem, const float* __restrict__ pe,
           float* __restrict__ z, int t) {
  const int gid = blockIdx.x*256 + threadIdx.x;
  if (gid >= 128*L_SEQ) return;
  const int e0 = blockIdx.y * 8;
  const int n = gid / L_SEQ, row = gid - n*L_SEQ;
  float acc[8];
  if (row == 0) {
    #pragma unroll
    for (int k = 0; k < 8; k++) acc[k] = b_in[e0+k];
    const float* q = queries + n*32;
    const float* v = values + (size_t)((n>>2)*8 + t)*32;
    for (int c = 0; c < 32; c++) {
      const float qc = q[c], vc = v[c];
      #pragma unroll
      for (int k = 0; k < 8; k++) acc[k] += qc*W_in[c*32+e0+k] + vc*W_in[(32+c)*32+e0+k];
    }
  } else {
    #pragma unroll
    for (int k = 0; k < 8; k++) acc[k] = b_me[e0+k];
    const float* mr = mem + ((size_t)n*256 + (row-1))*32;
    for (int c = 0; c < 32; c++) {
      const float mc = mr[c];
      #pragma unroll
      for (int k = 0; k < 8; k++) acc[k] += mc*W_me[c*32+e0+k];
    }
  }
  float* zr = z + (size_t)gid*32 + e0;
  const float* per = pe + row*32 + e0;
  #pragma unroll
  for (int k = 0; k < 8; k++) zr[k] = acc[k] + per[k];
}

// ---------------------------------------------------------------------------
// grid (512, 3): blockIdx.x = n*4+h, blockIdx.y = which (0:K 1:V 2:Q-scaled)
__global__ __launch_bounds__(256, 2)
void k_proj(const float* __restrict__ z,
            const float* __restrict__ Wq, const float* __restrict__ bq,
            const float* __restrict__ Wk, const float* __restrict__ bk,
            const float* __restrict__ Wv, const float* __restrict__ bv,
            float* __restrict__ Kg, float* __restrict__ Vg,
            float* __restrict__ Qg) {
  const int nh = blockIdx.x, which = blockIdx.y;
  const int n = nh >> 2, h = nh & 3;
  const float* W  = (which == 0) ? Wk : (which == 1) ? Wv : Wq;
  const float* bb = (which == 0) ? bk : (which == 1) ? bv : bq;
  float* out      = (which == 0) ? Kg : (which == 1) ? Vg : Qg;
  const float scale = (which == 2) ? SCALE : 1.0f;
  const float* zb = z + (size_t)n*L_SEQ*32;

  for (int r = threadIdx.x; r < L_SEQ; r += 256) {
    float acc[32];
    #pragma unroll
    for (int d = 0; d < 32; d++) acc[d] = bb[h*32+d];
    const float* zr = zb + r*32;
    for (int e = 0; e < 32; e++) {
      const float ze = zr[e];
      #pragma unroll
      for (int d = 0; d < 32; d++) acc[d] += ze * W[e*128 + h*32 + d];
    }
    float4* dst = (float4*)(out + ((size_t)nh*L_SEQ + r)*32);
    #pragma unroll
    for (int c = 0; c < 8; c++)
      dst[c] = make_float4(acc[4*c]*scale, acc[4*c+1]*scale, acc[4*c+2]*scale, acc[4*c+3]*scale);
  }
}

// ---------------------------------------------------------------------------
// One block per (n,h). Lane tid owns query row tid; row 256 by wave (h).
// K/V rows wave-uniform -> scalar/broadcast loads; 128-VGPR budget for
// q/o residency + load pipelining.
__global__ __launch_bounds__(256, 2)
void k_attn(const float* __restrict__ Qg, const float* __restrict__ Kg,
            const float* __restrict__ Vg, const float* __restrict__ Wo,
            float* __restrict__ headout) {
  const int nh = blockIdx.x;
  const int h = nh & 3;
  const int tid = threadIdx.x;
  const float* Kb = Kg + (size_t)nh*L_SEQ*32;
  const float* Vb = Vg + (size_t)nh*L_SEQ*32;
  const float* Qb = Qg + (size_t)nh*L_SEQ*32;
  const float* wo = Wo + h*1024;
  float* hob = headout + (size_t)nh*L_SEQ*32;

  float q[32];
  {
    const float4* qr = (const float4*)(Qb + (size_t)tid*32);
    #pragma unroll
    for (int c = 0; c < 8; c++) {
      const float4 t4 = qr[c];
      q[4*c] = t4.x; q[4*c+1] = t4.y; q[4*c+2] = t4.z; q[4*c+3] = t4.w;
    }
  }
  float o[32];
  #pragma unroll
  for (int d = 0; d < 32; d++) o[d] = 0.f;
  float m = -1e30f, sum = 0.f;

  #pragma unroll 1
  for (int ch = 0; ch < 32; ch++) {
    float sc[8];
    #pragma unroll
    for (int jj = 0; jj < 8; jj++) {
      const int l = ch*8 + jj;
      const float4* kr = (const float4*)(Kb + l*32);
      float s0 = 0.f, s1 = 0.f, s2 = 0.f, s3 = 0.f;
      #pragma unroll
      for (int c = 0; c < 8; c++) {
        const float4 kc = kr[c];
        s0 += q[4*c]*kc.x;   s1 += q[4*c+1]*kc.y;
        s2 += q[4*c+2]*kc.z; s3 += q[4*c+3]*kc.w;
      }
      sc[jj] = (s0 + s1) + (s2 + s3);
    }
    float cm = sc[0];
    #pragma unroll
    for (int jj = 1; jj < 8; jj++) cm = fmaxf(cm, sc[jj]);
    if (!__all(cm <= m)) {
      const float nm = fmaxf(m, cm);
      const float e0 = __expf(m - nm);
      sum *= e0;
      #pragma unroll
      for (int d = 0; d < 32; d++) o[d] *= e0;
      m = nm;
    }
    #pragma unroll
    for (int jj = 0; jj < 8; jj++) {
      const int l = ch*8 + jj;
      const float p = __expf(sc[jj] - m);
      sum += p;
      const float4* vr = (const float4*)(Vb + l*32);
      #pragma unroll
      for (int c = 0; c < 8; c++) {
        const float4 vc = vr[c];
        o[4*c]   += p*vc.x; o[4*c+1] += p*vc.y;
        o[4*c+2] += p*vc.z; o[4*c+3] += p*vc.w;
      }
    }
  }
  {  // key 256
    const float4* kr = (const float4*)(Kb + 256*32);
    float s0 = 0.f, s1 = 0.f, s2 = 0.f, s3 = 0.f;
    #pragma unroll
    for (int c = 0; c < 8; c++) {
      const float4 kc = kr[c];
      s0 += q[4*c]*kc.x;   s1 += q[4*c+1]*kc.y;
      s2 += q[4*c+2]*kc.z; s3 += q[4*c+3]*kc.w;
    }
    const float x = (s0 + s1) + (s2 + s3);
    const float nm = fmaxf(m, x);
    const float e0 = __expf(m - nm), p = __expf(x - nm);
    sum = sum*e0 + p;
    const float4* vr = (const float4*)(Vb + 256*32);
    #pragma unroll
    for (int c = 0; c < 8; c++) {
      const float4 vc = vr[c];
      o[4*c]   = o[4*c]*e0   + p*vc.x; o[4*c+1] = o[4*c+1]*e0 + p*vc.y;
      o[4*c+2] = o[4*c+2]*e0 + p*vc.z; o[4*c+3] = o[4*c+3]*e0 + p*vc.w;
    }
    m = nm;
  }
  {  // output projection (Wo wave-uniform)
    const float inv = 1.f/sum;
    float outv[32];
    #pragma unroll 4
    for (int d = 0; d < 32; d++) {
      float a = 0.f;
      #pragma unroll
      for (int kd = 0; kd < 32; kd++) a += o[kd]*wo[kd*32 + d];
      outv[d] = a*inv;
    }
    float4* dst = (float4*)(hob + (size_t)tid*32);
    #pragma unroll
    for (int c = 0; c < 8; c++)
      dst[c] = make_float4(outv[4*c], outv[4*c+1], outv[4*c+2], outv[4*c+3]);
  }
  // query row 256: one (rotating) wave, lanes split keys, butterfly merge
  if ((tid >> 6) == h) {
    const int lane = tid & 63;
    float q2[32];
    {
      const float4* qr = (const float4*)(Qb + 256*32);
      #pragma unroll
      for (int c = 0; c < 8; c++) {
        const float4 t4 = qr[c];
        q2[4*c] = t4.x; q2[4*c+1] = t4.y; q2[4*c+2] = t4.z; q2[4*c+3] = t4.w;
      }
    }
    float m2 = -1e30f, s2 = 0.f, o2[32];
    #pragma unroll
    for (int d = 0; d < 32; d++) o2[d] = 0.f;
    for (int l = lane; l < L_SEQ; l += 64) {
      const float4* kr = (const float4*)(Kb + l*32);
      const float4* vr = (const float4*)(Vb + l*32);
      float s0 = 0.f, s1 = 0.f, s2p = 0.f, s3 = 0.f;
      #pragma unroll
      for (int c = 0; c < 8; c++) {
        const float4 kc = kr[c];
        s0 += q2[4*c]*kc.x;   s1 += q2[4*c+1]*kc.y;
        s2p += q2[4*c+2]*kc.z; s3 += q2[4*c+3]*kc.w;
      }
      const float x = (s0 + s1) + (s2p + s3);
      const float nm = fmaxf(m2, x);
      const float e0 = __expf(m2 - nm), p = __expf(x - nm);
      s2 = s2*e0 + p;
      #pragma unroll
      for (int c = 0; c < 8; c++) {
        const float4 vc = vr[c];
        o2[4*c]   = o2[4*c]*e0   + p*vc.x; o2[4*c+1] = o2[4*c+1]*e0 + p*vc.y;
        o2[4*c+2] = o2[4*c+2]*e0 + p*vc.z; o2[4*c+3] = o2[4*c+3]*e0 + p*vc.w;
      }
      m2 = nm;
    }
    #pragma unroll 1
    for (int off = 1; off < 64; off <<= 1) {
      const float om = __shfl_xor(m2, off);
      const float os = __shfl_xor(s2, off);
      const float nm = fmaxf(m2, om);
      const float me = __expf(m2 - nm), oe = __expf(om - nm);
      s2 = s2*me + os*oe;
      #pragma unroll
      for (int d = 0; d < 32; d++) o2[d] = o2[d]*me + __shfl_xor(o2[d], off)*oe;
      m2 = nm;
    }
    if (lane < 32) {
      const float inv = 1.f/s2;
      float a = 0.f;
      #pragma unroll
      for (int kd = 0; kd < 32; kd++) a += o2[kd]*wo[kd*32 + lane];
      hob[256*32 + lane] = a*inv;
    }
  }
}

// ---------------------------------------------------------------------------
// grid 257 blocks x 256. Waves 0/1 = parts 0/1 of rows 0..63; waves 2/3 of
// rows 64..127. part is wave-uniform -> all weight reads scalarize.
// part-1 partials cross to part-0 via padded LDS.
__global__ __launch_bounds__(256, 2)
void k_ffln(const float* __restrict__ headout, const float* __restrict__ z,
            const float* __restrict__ bo,
            const float* __restrict__ W_f1, const float* __restrict__ b_f1,
            const float* __restrict__ W_f2, const float* __restrict__ b_f2,
            const float* __restrict__ ln_g, const float* __restrict__ ln_b,
            const float* __restrict__ W_out, const float* __restrict__ b_out,
            float* __restrict__ nf, float* __restrict__ outp, int t) {
  __shared__ float ybuf[128][33];
  const int tid = threadIdx.x;
  const int lane = tid & 63;
  const int part = (tid >> 6) & 1;
  const int rib = ((tid >> 7) << 6) + lane;           // row in block, 0..127
  const int rowid = blockIdx.x*128 + rib;             // 0..32895 (exact)
  const int n = rowid / L_SEQ, row = rowid - n*L_SEQ;

  float att[32];
  const float* hob = headout + (size_t)n*4*L_SEQ*32 + (size_t)row*32;
  const float* zr = z + (size_t)rowid*32;
  #pragma unroll
  for (int e = 0; e < 32; e++)
    att[e] = bo[e] + zr[e] + hob[e] + hob[L_SEQ*32 + e]
           + hob[2*L_SEQ*32 + e] + hob[3*L_SEQ*32 + e];
  float mu = 0.f;
  #pragma unroll
  for (int e = 0; e < 32; e++) mu += att[e];
  mu *= (1.f/32.f);
  float var = 0.f;
  #pragma unroll
  for (int e = 0; e < 32; e++) { const float d = att[e]-mu; var += d*d; }
  var *= (1.f/32.f);
  float rstd = 1.f/sqrtf(var + 1e-6f);
  #pragma unroll
  for (int e = 0; e < 32; e++) att[e] = (att[e]-mu)*rstd*ln_g[e] + ln_b[e];

  // FF half: j in [part*64, part*64+64)  (wave-uniform j)
  float y[32];
  #pragma unroll
  for (int e = 0; e < 32; e++) y[e] = 0.f;
  const int j0 = part*64;
  #pragma unroll 1
  for (int jj = 0; jj < 64; jj++) {
    const int j = j0 + jj;
    float hv = b_f1[j];
    #pragma unroll
    for (int e = 0; e < 32; e++) hv += att[e]*W_f1[e*128 + j];
    hv = fmaxf(hv, 0.f);
    #pragma unroll
    for (int e = 0; e < 32; e++) y[e] += hv*W_f2[j*32 + e];
  }
  if (part == 1) {
    #pragma unroll
    for (int e = 0; e < 32; e++) ybuf[rib][e] = y[e];
  }
  __syncthreads();
  if (part == 1) return;

  #pragma unroll
  for (int e = 0; e < 32; e++) y[e] += ybuf[rib][e] + b_f2[e] + att[e];

  mu = 0.f;
  #pragma unroll
  for (int e = 0; e < 32; e++) mu += y[e];
  mu *= (1.f/32.f);
  var = 0.f;
  #pragma unroll
  for (int e = 0; e < 32; e++) { const float d = y[e]-mu; var += d*d; }
  var *= (1.f/32.f);
  rstd = 1.f/sqrtf(var + 1e-6f);
  float nfv[32];
  #pragma unroll
  for (int e = 0; e < 32; e++) nfv[e] = (y[e]-mu)*rstd*ln_g[e] + ln_b[e];

  float4* nr = (float4*)(nf + (size_t)rowid*32);
  #pragma unroll
  for (int c = 0; c < 8; c++)
    nr[c] = make_float4(nfv[4*c], nfv[4*c+1], nfv[4*c+2], nfv[4*c+3]);

  if (t == 7 && row == 0) {
    float a = b_out[0];
    #pragma unroll
    for (int e = 0; e < 32; e++) a += nfv[e]*W_out[e];
    outp[n] = a;
  }
}

// ---------------------------------------------------------------------------
// Fused: gated memory update (rows>=1) + next step's z (all rows).
// grid 129 x 256, one thread per z row; tnext = t+1 for the row-0 embed.
__global__ __launch_bounds__(256, 2)
void k_memaug(const float* __restrict__ queries, const float* __restrict__ values,
              const float* __restrict__ W_in, const float* __restrict__ b_in,
              const float* __restrict__ W_me, const float* __restrict__ b_me,
              const float* __restrict__ W_mi, const float* __restrict__ b_mi,
              const float* __restrict__ nf, const float* __restrict__ pe,
              float* __restrict__ mem, float* __restrict__ z, int tnext) {
  const int gid = blockIdx.x*256 + threadIdx.x;
  if (gid >= 128*L_SEQ) return;
  const int n = gid / L_SEQ, row = gid - n*L_SEQ;
  float acc[32];
  if (row == 0) {
    #pragma unroll
    for (int e = 0; e < 32; e++) acc[e] = b_in[e];
    const float* q = queries + n*32;
    const float* v = values + (size_t)((n>>2)*8 + tnext)*32;
    for (int c = 0; c < 32; c++) {
      const float qc = q[c], vc = v[c];
      #pragma unroll
      for (int e = 0; e < 32; e++) acc[e] += qc*W_in[c*32+e] + vc*W_in[(32+c)*32+e];
    }
  } else {
    // gated memory update, mem row stays in registers
    float xr[32];
    const float* x = nf + (size_t)gid*32;
    #pragma unroll
    for (int e = 0; e < 32; e++) xr[e] = x[e];
    float mi0 = b_mi[0];
    #pragma unroll
    for (int e = 0; e < 32; e++) mi0 += xr[e]*W_mi[e*33];
    const float cs = 1.f/(1.f + expf(-mi0));
    const float ga = 1.f/(1.f + expf(cs));    // sigmoid(-cs)
    const float gb = 1.f/(1.f + expf(-cs));   // sigmoid(cs)
    float* mr = mem + ((size_t)n*256 + (row-1))*32;
    float mnew[32];
    #pragma unroll 1
    for (int c = 0; c < 32; c++) {
      float mic = b_mi[1+c];
      #pragma unroll
      for (int e = 0; e < 32; e++) mic += xr[e]*W_mi[e*33 + 1 + c];
      mnew[c] = ga*mr[c] + gb*mic;
    }
    #pragma unroll
    for (int c = 0; c < 8; c++)
      ((float4*)mr)[c] = make_float4(mnew[4*c], mnew[4*c+1], mnew[4*c+2], mnew[4*c+3]);
    // z row = mnew @ W_me + b_me
    #pragma unroll
    for (int e = 0; e < 32; e++) acc[e] = b_me[e];
    for (int c = 0; c < 32; c++) {
      const float mc = mnew[c];
      #pragma unroll
      for (int e = 0; e < 32; e++) acc[e] += mc*W_me[c*32+e];
    }
  }
  const float* per = pe + row*32;
  float4* zr = (float4*)(z + (size_t)gid*32);
  #pragma unroll
  for (int c = 0; c < 8; c++)
    zr[c] = make_float4(acc[4*c]+per[4*c], acc[4*c+1]+per[4*c+1],
                        acc[4*c+2]+per[4*c+2], acc[4*c+3]+per[4*c+3]);
}

// ---------------------------------------------------------------------------
extern "C" void kernel_launch(void* const* d_in, const int* in_sizes, int n_in,
                              void* d_out, int out_size, void* d_ws, size_t ws_size,
                              hipStream_t stream) {
  const float* queries = (const float*)d_in[0];
  const float* values  = (const float*)d_in[1];
  const float* W_in = (const float*)d_in[2];   const float* b_in = (const float*)d_in[3];
  const float* W_me = (const float*)d_in[4];   const float* b_me = (const float*)d_in[5];
  const float* Wq   = (const float*)d_in[6];   const float* bq   = (const float*)d_in[7];
  const float* Wk   = (const float*)d_in[8];   const float* bk   = (const float*)d_in[9];
  const float* Wv   = (const float*)d_in[10];  const float* bv   = (const float*)d_in[11];
  const float* Wo   = (const float*)d_in[12];  const float* bo   = (const float*)d_in[13];
  const float* W_f1 = (const float*)d_in[14];  const float* b_f1 = (const float*)d_in[15];
  const float* W_f2 = (const float*)d_in[16];  const float* b_f2 = (const float*)d_in[17];
  const float* ln_g = (const float*)d_in[18];  const float* ln_b = (const float*)d_in[19];
  const float* W_out= (const float*)d_in[20];  const float* b_out= (const float*)d_in[21];
  const float* W_mi = (const float*)d_in[22];  const float* b_mi = (const float*)d_in[23];

  float* ws  = (float*)d_ws;
  float* mem = ws;                 // MEM_SZ
  float* z   = mem + MEM_SZ;       // Z_SZ
  float* ho  = z   + Z_SZ;         // HO_SZ
  float* nf  = ho  + HO_SZ;        // NF_SZ
  float* pe  = nf  + NF_SZ;        // PE_SZ
  float* Kg  = pe  + PE_SZ;        // QKV_SZ
  float* Vg  = Kg  + QKV_SZ;       // QKV_SZ
  float* Qg  = Vg  + QKV_SZ;       // QKV_SZ
  float* outp = (float*)d_out;     // 128 floats

  k_init<<<MEM_SZ/256, 256, 0, stream>>>(mem);
  k_pe<<<(L_SEQ*32 + 255)/256, 256, 0, stream>>>(pe);
  k_aug<<<dim3(129, 4), 256, 0, stream>>>(queries, values, W_in, b_in,
                                          W_me, b_me, mem, pe, z, 0);
  for (int t = 0; t < 8; t++) {
    k_proj<<<dim3(512, 3), 256, 0, stream>>>(z, Wq, bq, Wk, bk, Wv, bv, Kg, Vg, Qg);
    k_attn<<<512, 256, 0, stream>>>(Qg, Kg, Vg, Wo, ho);
    k_ffln<<<257, 256, 0, stream>>>(ho, z, bo, W_f1, b_f1, W_f2, b_f2,
                                    ln_g, ln_b, W_out, b_out, nf, outp, t);
    if (t < 7)
      k_memaug<<<129, 256, 0, stream>>>(queries, values, W_in, b_in, W_me, b_me,
                                        W_mi, b_mi, nf, pe, mem, z, t+1);
  }
}

// Round 7
// 1952.800 us; speedup vs baseline: 1.9520x; 1.5983x over previous
//
#include <hip/hip_runtime.h>
#include <math.h>

// ---------------------------------------------------------------------------
// MemoryLayerAttention: 8-step recurrent transformer cell.
//   N=128 sequences, L=257 rows, E=32, CH=4 heads, KD=32, FF=128, R=256, C=32.
// Per step (graph-captured):
//   k_proj   : K,V,Q(n,h,l,32) -> global scratch (Q pre-scaled)
//   k_attn   : block=(nh, 64-row group); 4 waves = 4 key quarters over the
//              SAME rows (wave idx made uniform via readfirstlane -> scalar
//              K/V loads); LDS merge of partial softmax; 16 waves/CU
//   k_ffln   : block=64 rows x 4 FF-quarters (readfirstlane-uniform j)
//   k_memaug : gated mem update fused with next step's z computation
// ---------------------------------------------------------------------------

#define L_SEQ 257
#define SCALE 0.17677669529663689f   // 1/sqrt(32)

// ws layout (floats)
#define MEM_SZ  (128*256*32)
#define Z_SZ    (128*257*32)
#define HO_SZ   (128*4*257*32)
#define NF_SZ   (128*257*32)
#define PE_SZ   (L_SEQ*32)
#define QKV_SZ  (512*L_SEQ*32)

// ---------------------------------------------------------------------------
__global__ void k_init(float* __restrict__ mem) {
  const int i = blockIdx.x*256 + threadIdx.x;
  if (i < MEM_SZ) mem[i] = 1e-6f;
}

// PE computed in double to match numpy's float64 path; runs once per call.
__global__ void k_pe(float* __restrict__ pe) {
  const int i = blockIdx.x*256 + threadIdx.x;
  if (i >= L_SEQ*32) return;
  const int row = i >> 5, e = i & 31;
  const int k = e >> 1;
  const double p10 = pow(10000.0, (double)(2*k)/32.0);
  const double ang = (double)row / p10;
  pe[i] = (float)((e & 1) ? cos(ang) : sin(ang));
}

// ---------------------------------------------------------------------------
// t=0 only. grid (129, 4): blockIdx.y = e-quarter (uniform weight reads)
__global__ __launch_bounds__(256, 2)
void k_aug(const float* __restrict__ queries, const float* __restrict__ values,
           const float* __restrict__ W_in, const float* __restrict__ b_in,
           const float* __restrict__ W_me, const float* __restrict__ b_me,
           const float* __restrict__ mem, const float* __restrict__ pe,
           float* __restrict__ z, int t) {
  const int gid = blockIdx.x*256 + threadIdx.x;
  if (gid >= 128*L_SEQ) return;
  const int e0 = blockIdx.y * 8;
  const int n = gid / L_SEQ, row = gid - n*L_SEQ;
  float acc[8];
  if (row == 0) {
    #pragma unroll
    for (int k = 0; k < 8; k++) acc[k] = b_in[e0+k];
    const float* q = queries + n*32;
    const float* v = values + (size_t)((n>>2)*8 + t)*32;
    for (int c = 0; c < 32; c++) {
      const float qc = q[c], vc = v[c];
      #pragma unroll
      for (int k = 0; k < 8; k++) acc[k] += qc*W_in[c*32+e0+k] + vc*W_in[(32+c)*32+e0+k];
    }
  } else {
    #pragma unroll
    for (int k = 0; k < 8; k++) acc[k] = b_me[e0+k];
    const float* mr = mem + ((size_t)n*256 + (row-1))*32;
    for (int c = 0; c < 32; c++) {
      const float mc = mr[c];
      #pragma unroll
      for (int k = 0; k < 8; k++) acc[k] += mc*W_me[c*32+e0+k];
    }
  }
  float* zr = z + (size_t)gid*32 + e0;
  const float* per = pe + row*32 + e0;
  #pragma unroll
  for (int k = 0; k < 8; k++) zr[k] = acc[k] + per[k];
}

// ---------------------------------------------------------------------------
// grid (512, 3): blockIdx.x = n*4+h, blockIdx.y = which (0:K 1:V 2:Q-scaled)
__global__ __launch_bounds__(256, 2)
void k_proj(const float* __restrict__ z,
            const float* __restrict__ Wq, const float* __restrict__ bq,
            const float* __restrict__ Wk, const float* __restrict__ bk,
            const float* __restrict__ Wv, const float* __restrict__ bv,
            float* __restrict__ Kg, float* __restrict__ Vg,
            float* __restrict__ Qg) {
  const int nh = blockIdx.x, which = blockIdx.y;
  const int n = nh >> 2, h = nh & 3;
  const float* W  = (which == 0) ? Wk : (which == 1) ? Wv : Wq;
  const float* bb = (which == 0) ? bk : (which == 1) ? bv : bq;
  float* out      = (which == 0) ? Kg : (which == 1) ? Vg : Qg;
  const float scale = (which == 2) ? SCALE : 1.0f;
  const float* zb = z + (size_t)n*L_SEQ*32;

  for (int r = threadIdx.x; r < L_SEQ; r += 256) {
    float acc[32];
    #pragma unroll
    for (int d = 0; d < 32; d++) acc[d] = bb[h*32+d];
    const float4* z4 = (const float4*)(zb + r*32);
    #pragma unroll 2
    for (int c8 = 0; c8 < 8; c8++) {
      const float4 zc = z4[c8];
      const float zv[4] = {zc.x, zc.y, zc.z, zc.w};
      #pragma unroll
      for (int q = 0; q < 4; q++) {
        const int e = c8*4 + q;
        const float ze = zv[q];
        #pragma unroll
        for (int d = 0; d < 32; d++) acc[d] += ze * W[e*128 + h*32 + d];
      }
    }
    float4* dst = (float4*)(out + ((size_t)nh*L_SEQ + r)*32);
    #pragma unroll
    for (int c = 0; c < 8; c++)
      dst[c] = make_float4(acc[4*c]*scale, acc[4*c+1]*scale, acc[4*c+2]*scale, acc[4*c+3]*scale);
  }
}

// ---------------------------------------------------------------------------
// grid (512, 4): blockIdx = (nh, rowgroup). Wave w handles key quarter
// [w*64, w*64+64) (wave 3 also key 256) for the SAME 64 rows (rg*64+lane).
// wave is readfirstlane'd -> compiler-provable uniform -> K/V rows load as
// s_load (SGPR operands). Partial (m,s,o[32]) merged through LDS by wave 0.
// Row 256 done by rg==3 blocks.
__global__ __launch_bounds__(256, 4)
void k_attn(const float* __restrict__ Qg, const float* __restrict__ Kg,
            const float* __restrict__ Vg, const float* __restrict__ Wo,
            float* __restrict__ headout) {
  __shared__ float pbuf[3][64][35];
  const int nh = blockIdx.x, rg = blockIdx.y;
  const int h = nh & 3;
  const int tid = threadIdx.x;
  const int wave = __builtin_amdgcn_readfirstlane(tid >> 6);  // uniform!
  const int lane = tid & 63;
  const int row = rg*64 + lane;
  const float* Kb = Kg + (size_t)nh*L_SEQ*32;
  const float* Vb = Vg + (size_t)nh*L_SEQ*32;
  const float* Qb = Qg + (size_t)nh*L_SEQ*32;
  const float* wo = Wo + h*1024;
  float* hob = headout + (size_t)nh*L_SEQ*32;

  float q[32];
  {
    const float4* qr = (const float4*)(Qb + (size_t)row*32);
    #pragma unroll
    for (int c = 0; c < 8; c++) {
      const float4 t4 = qr[c];
      q[4*c] = t4.x; q[4*c+1] = t4.y; q[4*c+2] = t4.z; q[4*c+3] = t4.w;
    }
  }
  float o[32];
  #pragma unroll
  for (int d = 0; d < 32; d++) o[d] = 0.f;
  float m = -1e30f, sum = 0.f;
  const int l0 = wave*64;

  #pragma unroll 1
  for (int ch = 0; ch < 8; ch++) {
    float sc[8];
    #pragma unroll
    for (int jj = 0; jj < 8; jj++) {
      const int l = l0 + ch*8 + jj;
      const float4* kr = (const float4*)(Kb + l*32);
      float s0 = 0.f, s1 = 0.f, s2 = 0.f, s3 = 0.f;
      #pragma unroll
      for (int c = 0; c < 8; c++) {
        const float4 kc = kr[c];
        s0 += q[4*c]*kc.x;   s1 += q[4*c+1]*kc.y;
        s2 += q[4*c+2]*kc.z; s3 += q[4*c+3]*kc.w;
      }
      sc[jj] = (s0 + s1) + (s2 + s3);
    }
    float cm = sc[0];
    #pragma unroll
    for (int jj = 1; jj < 8; jj++) cm = fmaxf(cm, sc[jj]);
    if (!__all(cm <= m)) {
      const float nm = fmaxf(m, cm);
      const float e0 = __expf(m - nm);
      sum *= e0;
      #pragma unroll
      for (int d = 0; d < 32; d++) o[d] *= e0;
      m = nm;
    }
    #pragma unroll
    for (int jj = 0; jj < 8; jj++) {
      const int l = l0 + ch*8 + jj;
      const float p = __expf(sc[jj] - m);
      sum += p;
      const float4* vr = (const float4*)(Vb + l*32);
      #pragma unroll
      for (int c = 0; c < 8; c++) {
        const float4 vc = vr[c];
        o[4*c]   += p*vc.x; o[4*c+1] += p*vc.y;
        o[4*c+2] += p*vc.z; o[4*c+3] += p*vc.w;
      }
    }
  }
  if (wave == 3) {  // key 256
    const float4* kr = (const float4*)(Kb + 256*32);
    float s0 = 0.f, s1 = 0.f, s2 = 0.f, s3 = 0.f;
    #pragma unroll
    for (int c = 0; c < 8; c++) {
      const float4 kc = kr[c];
      s0 += q[4*c]*kc.x;   s1 += q[4*c+1]*kc.y;
      s2 += q[4*c+2]*kc.z; s3 += q[4*c+3]*kc.w;
    }
    const float x = (s0 + s1) + (s2 + s3);
    const float nm = fmaxf(m, x);
    const float e0 = __expf(m - nm), p = __expf(x - nm);
    sum = sum*e0 + p;
    const float4* vr = (const float4*)(Vb + 256*32);
    #pragma unroll
    for (int c = 0; c < 8; c++) {
      const float4 vc = vr[c];
      o[4*c]   = o[4*c]*e0   + p*vc.x; o[4*c+1] = o[4*c+1]*e0 + p*vc.y;
      o[4*c+2] = o[4*c+2]*e0 + p*vc.z; o[4*c+3] = o[4*c+3]*e0 + p*vc.w;
    }
    m = nm;
  }
  // stash partials (waves 1..3)
  if (wave > 0) {
    pbuf[wave-1][lane][0] = m;
    pbuf[wave-1][lane][1] = sum;
    #pragma unroll
    for (int c = 0; c < 32; c++) pbuf[wave-1][lane][2+c] = o[c];
  }
  __syncthreads();
  if (wave == 0) {
    #pragma unroll 1
    for (int w = 0; w < 3; w++) {
      const float mw = pbuf[w][lane][0];
      const float sw = pbuf[w][lane][1];
      const float nm = fmaxf(m, mw);
      const float f = __expf(m - nm), g = __expf(mw - nm);
      sum = sum*f + sw*g;
      #pragma unroll
      for (int c = 0; c < 32; c++) o[c] = o[c]*f + g*pbuf[w][lane][2+c];
      m = nm;
    }
    const float inv = 1.f/sum;
    float outv[32];
    #pragma unroll 4
    for (int d = 0; d < 32; d++) {
      float a = 0.f;
      #pragma unroll
      for (int kd = 0; kd < 32; kd++) a += o[kd]*wo[kd*32 + d];
      outv[d] = a*inv;
    }
    float4* dst = (float4*)(hob + (size_t)row*32);
    #pragma unroll
    for (int c = 0; c < 8; c++)
      dst[c] = make_float4(outv[4*c], outv[4*c+1], outv[4*c+2], outv[4*c+3]);
  }

  // ---- query row 256: only rg==3 blocks ----
  if (rg == 3) {
    float q2[32];
    {
      const float4* qr = (const float4*)(Qb + 256*32);   // uniform
      #pragma unroll
      for (int c = 0; c < 8; c++) {
        const float4 t4 = qr[c];
        q2[4*c] = t4.x; q2[4*c+1] = t4.y; q2[4*c+2] = t4.z; q2[4*c+3] = t4.w;
      }
    }
    // this wave's quarter: key l0+lane (one per lane, divergent by design)
    float m2, s2, o2[32];
    {
      const int l = l0 + lane;
      const float4* kr = (const float4*)(Kb + l*32);
      const float4* vr = (const float4*)(Vb + l*32);
      float s0 = 0.f, s1 = 0.f, sp = 0.f, s3 = 0.f;
      #pragma unroll
      for (int c = 0; c < 8; c++) {
        const float4 kc = kr[c];
        s0 += q2[4*c]*kc.x;   s1 += q2[4*c+1]*kc.y;
        sp += q2[4*c+2]*kc.z; s3 += q2[4*c+3]*kc.w;
      }
      m2 = (s0 + s1) + (sp + s3);
      s2 = 1.f;
      #pragma unroll
      for (int c = 0; c < 8; c++) {
        const float4 vc = vr[c];
        o2[4*c] = vc.x; o2[4*c+1] = vc.y; o2[4*c+2] = vc.z; o2[4*c+3] = vc.w;
      }
    }
    if (wave == 3 && lane == 0) {  // key 256
      const float4* kr = (const float4*)(Kb + 256*32);
      const float4* vr = (const float4*)(Vb + 256*32);
      float s0 = 0.f, s1 = 0.f, sp = 0.f, s3 = 0.f;
      #pragma unroll
      for (int c = 0; c < 8; c++) {
        const float4 kc = kr[c];
        s0 += q2[4*c]*kc.x;   s1 += q2[4*c+1]*kc.y;
        sp += q2[4*c+2]*kc.z; s3 += q2[4*c+3]*kc.w;
      }
      const float x = (s0 + s1) + (sp + s3);
      const float nm = fmaxf(m2, x);
      const float e0 = __expf(m2 - nm), p = __expf(x - nm);
      s2 = s2*e0 + p;
      #pragma unroll
      for (int c = 0; c < 8; c++) {
        const float4 vc = vr[c];
        o2[4*c]   = o2[4*c]*e0   + p*vc.x; o2[4*c+1] = o2[4*c+1]*e0 + p*vc.y;
        o2[4*c+2] = o2[4*c+2]*e0 + p*vc.z; o2[4*c+3] = o2[4*c+3]*e0 + p*vc.w;
      }
      m2 = nm;
    }
    // butterfly within wave
    #pragma unroll 1
    for (int off = 1; off < 64; off <<= 1) {
      const float om = __shfl_xor(m2, off);
      const float os = __shfl_xor(s2, off);
      const float nm = fmaxf(m2, om);
      const float me = __expf(m2 - nm), oe = __expf(om - nm);
      s2 = s2*me + os*oe;
      #pragma unroll
      for (int d = 0; d < 32; d++) o2[d] = o2[d]*me + __shfl_xor(o2[d], off)*oe;
      m2 = nm;
    }
    __syncthreads();   // pbuf free to reuse (wave0 merge done)
    if (lane == 0) {
      pbuf[0][wave][0] = m2;
      pbuf[0][wave][1] = s2;
      #pragma unroll
      for (int c = 0; c < 32; c++) pbuf[0][wave][2+c] = o2[c];
    }
    __syncthreads();
    if (wave == 0) {
      float mw[4], fw[4];
      #pragma unroll
      for (int w = 0; w < 4; w++) mw[w] = pbuf[0][w][0];
      float M = fmaxf(fmaxf(mw[0], mw[1]), fmaxf(mw[2], mw[3]));
      float S = 0.f;
      #pragma unroll
      for (int w = 0; w < 4; w++) {
        fw[w] = __expf(mw[w] - M);
        S += pbuf[0][w][1]*fw[w];
      }
      const int c = lane & 31;
      float om = 0.f;
      #pragma unroll
      for (int w = 0; w < 4; w++) om += fw[w]*pbuf[0][w][2+c];
      // Wo projection via shfl transpose
      float a = 0.f;
      #pragma unroll
      for (int kd = 0; kd < 32; kd++) a += __shfl(om, kd) * wo[kd*32 + c];
      if (lane < 32) hob[256*32 + c] = a / S;
    }
  }
}

// ---------------------------------------------------------------------------
// grid 514 x 256. Block = 64 rows; wave w computes FF units j in
// [w*32, w*32+32) (readfirstlane-uniform -> scalar weight loads); LDS merge.
__global__ __launch_bounds__(256, 2)
void k_ffln(const float* __restrict__ headout, const float* __restrict__ z,
            const float* __restrict__ bo,
            const float* __restrict__ W_f1, const float* __restrict__ b_f1,
            const float* __restrict__ W_f2, const float* __restrict__ b_f2,
            const float* __restrict__ ln_g, const float* __restrict__ ln_b,
            const float* __restrict__ W_out, const float* __restrict__ b_out,
            float* __restrict__ nf, float* __restrict__ outp, int t) {
  __shared__ float ybuf[3][64][33];
  const int tid = threadIdx.x;
  const int wave = __builtin_amdgcn_readfirstlane(tid >> 6);  // uniform!
  const int lane = tid & 63;
  const int rowid = blockIdx.x*64 + lane;             // 514*64 = 32896 exact
  const int n = rowid / L_SEQ, row = rowid - n*L_SEQ;

  float att[32];
  const float* hob = headout + (size_t)n*4*L_SEQ*32 + (size_t)row*32;
  const float* zr = z + (size_t)rowid*32;
  #pragma unroll
  for (int e = 0; e < 32; e++)
    att[e] = bo[e] + zr[e] + hob[e] + hob[L_SEQ*32 + e]
           + hob[2*L_SEQ*32 + e] + hob[3*L_SEQ*32 + e];
  float mu = 0.f;
  #pragma unroll
  for (int e = 0; e < 32; e++) mu += att[e];
  mu *= (1.f/32.f);
  float var = 0.f;
  #pragma unroll
  for (int e = 0; e < 32; e++) { const float d = att[e]-mu; var += d*d; }
  var *= (1.f/32.f);
  float rstd = 1.f/sqrtf(var + 1e-6f);
  #pragma unroll
  for (int e = 0; e < 32; e++) att[e] = (att[e]-mu)*rstd*ln_g[e] + ln_b[e];

  // FF quarter: j in [wave*32, wave*32+32)
  float y[32];
  #pragma unroll
  for (int e = 0; e < 32; e++) y[e] = 0.f;
  const int j0 = wave*32;
  #pragma unroll 1
  for (int jj = 0; jj < 32; jj++) {
    const int j = j0 + jj;
    float hv = b_f1[j];
    #pragma unroll
    for (int e = 0; e < 32; e++) hv += att[e]*W_f1[e*128 + j];
    hv = fmaxf(hv, 0.f);
    #pragma unroll
    for (int e = 0; e < 32; e++) y[e] += hv*W_f2[j*32 + e];
  }
  if (wave > 0) {
    #pragma unroll
    for (int e = 0; e < 32; e++) ybuf[wave-1][lane][e] = y[e];
  }
  __syncthreads();
  if (wave > 0) return;

  #pragma unroll
  for (int e = 0; e < 32; e++)
    y[e] += ybuf[0][lane][e] + ybuf[1][lane][e] + ybuf[2][lane][e]
          + b_f2[e] + att[e];

  mu = 0.f;
  #pragma unroll
  for (int e = 0; e < 32; e++) mu += y[e];
  mu *= (1.f/32.f);
  var = 0.f;
  #pragma unroll
  for (int e = 0; e < 32; e++) { const float d = y[e]-mu; var += d*d; }
  var *= (1.f/32.f);
  rstd = 1.f/sqrtf(var + 1e-6f);
  float nfv[32];
  #pragma unroll
  for (int e = 0; e < 32; e++) nfv[e] = (y[e]-mu)*rstd*ln_g[e] + ln_b[e];

  float4* nr = (float4*)(nf + (size_t)rowid*32);
  #pragma unroll
  for (int c = 0; c < 8; c++)
    nr[c] = make_float4(nfv[4*c], nfv[4*c+1], nfv[4*c+2], nfv[4*c+3]);

  if (t == 7 && row == 0) {
    float a = b_out[0];
    #pragma unroll
    for (int e = 0; e < 32; e++) a += nfv[e]*W_out[e];
    outp[n] = a;
  }
}

// ---------------------------------------------------------------------------
// Fused: gated memory update (rows>=1) + next step's z (all rows).
// grid 129 x 256, one thread per z row; tnext = t+1 for the row-0 embed.
__global__ __launch_bounds__(256, 2)
void k_memaug(const float* __restrict__ queries, const float* __restrict__ values,
              const float* __restrict__ W_in, const float* __restrict__ b_in,
              const float* __restrict__ W_me, const float* __restrict__ b_me,
              const float* __restrict__ W_mi, const float* __restrict__ b_mi,
              const float* __restrict__ nf, const float* __restrict__ pe,
              float* __restrict__ mem, float* __restrict__ z, int tnext) {
  const int gid = blockIdx.x*256 + threadIdx.x;
  if (gid >= 128*L_SEQ) return;
  const int n = gid / L_SEQ, row = gid - n*L_SEQ;
  float acc[32];
  if (row == 0) {
    #pragma unroll
    for (int e = 0; e < 32; e++) acc[e] = b_in[e];
    const float* q = queries + n*32;
    const float* v = values + (size_t)((n>>2)*8 + tnext)*32;
    for (int c = 0; c < 32; c++) {
      const float qc = q[c], vc = v[c];
      #pragma unroll
      for (int e = 0; e < 32; e++) acc[e] += qc*W_in[c*32+e] + vc*W_in[(32+c)*32+e];
    }
  } else {
    float xr[32];
    const float* x = nf + (size_t)gid*32;
    #pragma unroll
    for (int e = 0; e < 32; e++) xr[e] = x[e];
    float mi0 = b_mi[0];
    #pragma unroll
    for (int e = 0; e < 32; e++) mi0 += xr[e]*W_mi[e*33];
    const float cs = 1.f/(1.f + expf(-mi0));
    const float ga = 1.f/(1.f + expf(cs));    // sigmoid(-cs)
    const float gb = 1.f/(1.f + expf(-cs));   // sigmoid(cs)
    float* mr = mem + ((size_t)n*256 + (row-1))*32;
    float mnew[32];
    #pragma unroll 1
    for (int c = 0; c < 32; c++) {
      float mic = b_mi[1+c];
      #pragma unroll
      for (int e = 0; e < 32; e++) mic += xr[e]*W_mi[e*33 + 1 + c];
      mnew[c] = ga*mr[c] + gb*mic;
    }
    #pragma unroll
    for (int c = 0; c < 8; c++)
      ((float4*)mr)[c] = make_float4(mnew[4*c], mnew[4*c+1], mnew[4*c+2], mnew[4*c+3]);
    #pragma unroll
    for (int e = 0; e < 32; e++) acc[e] = b_me[e];
    for (int c = 0; c < 32; c++) {
      const float mc = mnew[c];
      #pragma unroll
      for (int e = 0; e < 32; e++) acc[e] += mc*W_me[c*32+e];
    }
  }
  const float* per = pe + row*32;
  float4* zr = (float4*)(z + (size_t)gid*32);
  #pragma unroll
  for (int c = 0; c < 8; c++)
    zr[c] = make_float4(acc[4*c]+per[4*c], acc[4*c+1]+per[4*c+1],
                        acc[4*c+2]+per[4*c+2], acc[4*c+3]+per[4*c+3]);
}

// ---------------------------------------------------------------------------
extern "C" void kernel_launch(void* const* d_in, const int* in_sizes, int n_in,
                              void* d_out, int out_size, void* d_ws, size_t ws_size,
                              hipStream_t stream) {
  const float* queries = (const float*)d_in[0];
  const float* values  = (const float*)d_in[1];
  const float* W_in = (const float*)d_in[2];   const float* b_in = (const float*)d_in[3];
  const float* W_me = (const float*)d_in[4];   const float* b_me = (const float*)d_in[5];
  const float* Wq   = (const float*)d_in[6];   const float* bq   = (const float*)d_in[7];
  const float* Wk   = (const float*)d_in[8];   const float* bk   = (const float*)d_in[9];
  const float* Wv   = (const float*)d_in[10];  const float* bv   = (const float*)d_in[11];
  const float* Wo   = (const float*)d_in[12];  const float* bo   = (const float*)d_in[13];
  const float* W_f1 = (const float*)d_in[14];  const float* b_f1 = (const float*)d_in[15];
  const float* W_f2 = (const float*)d_in[16];  const float* b_f2 = (const float*)d_in[17];
  const float* ln_g = (const float*)d_in[18];  const float* ln_b = (const float*)d_in[19];
  const float* W_out= (const float*)d_in[20];  const float* b_out= (const float*)d_in[21];
  const float* W_mi = (const float*)d_in[22];  const float* b_mi = (const float*)d_in[23];

  float* ws  = (float*)d_ws;
  float* mem = ws;                 // MEM_SZ
  float* z   = mem + MEM_SZ;       // Z_SZ
  float* ho  = z   + Z_SZ;         // HO_SZ
  float* nf  = ho  + HO_SZ;        // NF_SZ
  float* pe  = nf  + NF_SZ;        // PE_SZ
  float* Kg  = pe  + PE_SZ;        // QKV_SZ
  float* Vg  = Kg  + QKV_SZ;       // QKV_SZ
  float* Qg  = Vg  + QKV_SZ;       // QKV_SZ
  float* outp = (float*)d_out;     // 128 floats

  k_init<<<MEM_SZ/256, 256, 0, stream>>>(mem);
  k_pe<<<(L_SEQ*32 + 255)/256, 256, 0, stream>>>(pe);
  k_aug<<<dim3(129, 4), 256, 0, stream>>>(queries, values, W_in, b_in,
                                          W_me, b_me, mem, pe, z, 0);
  for (int t = 0; t < 8; t++) {
    k_proj<<<dim3(512, 3), 256, 0, stream>>>(z, Wq, bq, Wk, bk, Wv, bv, Kg, Vg, Qg);
    k_attn<<<dim3(512, 4), 256, 0, stream>>>(Qg, Kg, Vg, Wo, ho);
    k_ffln<<<514, 256, 0, stream>>>(ho, z, bo, W_f1, b_f1, W_f2, b_f2,
                                    ln_g, ln_b, W_out, b_out, nf, outp, t);
    if (t < 7)
      k_memaug<<<129, 256, 0, stream>>>(queries, values, W_in, b_in, W_me, b_me,
                                        W_mi, b_mi, nf, pe, mem, z, t+1);
  }
}

// Round 8
// 1750.940 us; speedup vs baseline: 2.1771x; 1.1153x over previous
//
#include <hip/hip_runtime.h>
#include <math.h>

// ---------------------------------------------------------------------------
// MemoryLayerAttention: 8-step recurrent transformer cell.
//   N=128 sequences, L=257 rows, E=32, CH=4 heads, KD=32, FF=128, R=256, C=32.
// Per step (graph-captured):
//   k_proj   : K,V,Q(n,h,l,32) -> global scratch (Q pre-scaled)
//   k_attn   : block=(nh, 64-row group); 4 waves = 4 key quarters over the
//              SAME rows (readfirstlane-uniform -> scalar K/V loads); LDS
//              merge; Wo projection distributed over all 4 waves
//   k_ffln   : block=64 rows x 4 FF-quarters; balanced all-wave merge
//   k_memaug : block=64 rows x 4 col-quarters; mnew exchanged via LDS
// ---------------------------------------------------------------------------

#define L_SEQ 257
#define SCALE 0.17677669529663689f   // 1/sqrt(32)

// ws layout (floats)
#define MEM_SZ  (128*256*32)
#define Z_SZ    (128*257*32)
#define HO_SZ   (128*4*257*32)
#define NF_SZ   (128*257*32)
#define PE_SZ   (L_SEQ*32)
#define QKV_SZ  (512*L_SEQ*32)

// ---------------------------------------------------------------------------
__global__ void k_init(float* __restrict__ mem) {
  const int i = blockIdx.x*256 + threadIdx.x;
  if (i < MEM_SZ) mem[i] = 1e-6f;
}

// PE computed in double to match numpy's float64 path; runs once per call.
__global__ void k_pe(float* __restrict__ pe) {
  const int i = blockIdx.x*256 + threadIdx.x;
  if (i >= L_SEQ*32) return;
  const int row = i >> 5, e = i & 31;
  const int k = e >> 1;
  const double p10 = pow(10000.0, (double)(2*k)/32.0);
  const double ang = (double)row / p10;
  pe[i] = (float)((e & 1) ? cos(ang) : sin(ang));
}

// ---------------------------------------------------------------------------
// t=0 only. grid (129, 4): blockIdx.y = e-quarter (uniform weight reads)
__global__ __launch_bounds__(256, 2)
void k_aug(const float* __restrict__ queries, const float* __restrict__ values,
           const float* __restrict__ W_in, const float* __restrict__ b_in,
           const float* __restrict__ W_me, const float* __restrict__ b_me,
           const float* __restrict__ mem, const float* __restrict__ pe,
           float* __restrict__ z, int t) {
  const int gid = blockIdx.x*256 + threadIdx.x;
  if (gid >= 128*L_SEQ) return;
  const int e0 = blockIdx.y * 8;
  const int n = gid / L_SEQ, row = gid - n*L_SEQ;
  float acc[8];
  if (row == 0) {
    #pragma unroll
    for (int k = 0; k < 8; k++) acc[k] = b_in[e0+k];
    const float* q = queries + n*32;
    const float* v = values + (size_t)((n>>2)*8 + t)*32;
    for (int c = 0; c < 32; c++) {
      const float qc = q[c], vc = v[c];
      #pragma unroll
      for (int k = 0; k < 8; k++) acc[k] += qc*W_in[c*32+e0+k] + vc*W_in[(32+c)*32+e0+k];
    }
  } else {
    #pragma unroll
    for (int k = 0; k < 8; k++) acc[k] = b_me[e0+k];
    const float* mr = mem + ((size_t)n*256 + (row-1))*32;
    for (int c = 0; c < 32; c++) {
      const float mc = mr[c];
      #pragma unroll
      for (int k = 0; k < 8; k++) acc[k] += mc*W_me[c*32+e0+k];
    }
  }
  float* zr = z + (size_t)gid*32 + e0;
  const float* per = pe + row*32 + e0;
  #pragma unroll
  for (int k = 0; k < 8; k++) zr[k] = acc[k] + per[k];
}

// ---------------------------------------------------------------------------
// grid (512, 3): blockIdx.x = n*4+h, blockIdx.y = which (0:K 1:V 2:Q-scaled)
__global__ __launch_bounds__(256, 2)
void k_proj(const float* __restrict__ z,
            const float* __restrict__ Wq, const float* __restrict__ bq,
            const float* __restrict__ Wk, const float* __restrict__ bk,
            const float* __restrict__ Wv, const float* __restrict__ bv,
            float* __restrict__ Kg, float* __restrict__ Vg,
            float* __restrict__ Qg) {
  const int nh = blockIdx.x, which = blockIdx.y;
  const int n = nh >> 2, h = nh & 3;
  const float* W  = (which == 0) ? Wk : (which == 1) ? Wv : Wq;
  const float* bb = (which == 0) ? bk : (which == 1) ? bv : bq;
  float* out      = (which == 0) ? Kg : (which == 1) ? Vg : Qg;
  const float scale = (which == 2) ? SCALE : 1.0f;
  const float* zb = z + (size_t)n*L_SEQ*32;

  for (int r = threadIdx.x; r < L_SEQ; r += 256) {
    float acc[32];
    #pragma unroll
    for (int d = 0; d < 32; d++) acc[d] = bb[h*32+d];
    const float4* z4 = (const float4*)(zb + r*32);
    #pragma unroll 2
    for (int c8 = 0; c8 < 8; c8++) {
      const float4 zc = z4[c8];
      const float zv[4] = {zc.x, zc.y, zc.z, zc.w};
      #pragma unroll
      for (int q = 0; q < 4; q++) {
        const int e = c8*4 + q;
        const float ze = zv[q];
        #pragma unroll
        for (int d = 0; d < 32; d++) acc[d] += ze * W[e*128 + h*32 + d];
      }
    }
    float4* dst = (float4*)(out + ((size_t)nh*L_SEQ + r)*32);
    #pragma unroll
    for (int c = 0; c < 8; c++)
      dst[c] = make_float4(acc[4*c]*scale, acc[4*c+1]*scale, acc[4*c+2]*scale, acc[4*c+3]*scale);
  }
}

// ---------------------------------------------------------------------------
// grid (512, 4): blockIdx = (nh, rowgroup). Wave w handles key quarter
// [w*64, w*64+64) (wave 3 also key 256) for the SAME 64 rows (rg*64+lane).
// Partials merged via LDS by wave 0; Wo projection distributed: each wave
// projects dims [w*8, w*8+8). Row 256 done by rg==3 blocks.
__global__ __launch_bounds__(256, 4)
void k_attn(const float* __restrict__ Qg, const float* __restrict__ Kg,
            const float* __restrict__ Vg, const float* __restrict__ Wo,
            float* __restrict__ headout) {
  __shared__ float pbuf[3][64][35];
  const int nh = blockIdx.x, rg = blockIdx.y;
  const int h = nh & 3;
  const int tid = threadIdx.x;
  const int wave = __builtin_amdgcn_readfirstlane(tid >> 6);  // uniform!
  const int lane = tid & 63;
  const int row = rg*64 + lane;
  const float* Kb = Kg + (size_t)nh*L_SEQ*32;
  const float* Vb = Vg + (size_t)nh*L_SEQ*32;
  const float* Qb = Qg + (size_t)nh*L_SEQ*32;
  const float* wo = Wo + h*1024;
  float* hob = headout + (size_t)nh*L_SEQ*32;

  float q[32];
  {
    const float4* qr = (const float4*)(Qb + (size_t)row*32);
    #pragma unroll
    for (int c = 0; c < 8; c++) {
      const float4 t4 = qr[c];
      q[4*c] = t4.x; q[4*c+1] = t4.y; q[4*c+2] = t4.z; q[4*c+3] = t4.w;
    }
  }
  float o[32];
  #pragma unroll
  for (int d = 0; d < 32; d++) o[d] = 0.f;
  float m = -1e30f, sum = 0.f;
  const int l0 = wave*64;

  #pragma unroll 2
  for (int ch = 0; ch < 8; ch++) {
    float sc[8];
    #pragma unroll
    for (int jj = 0; jj < 8; jj++) {
      const int l = l0 + ch*8 + jj;
      const float4* kr = (const float4*)(Kb + l*32);
      float s0 = 0.f, s1 = 0.f, s2 = 0.f, s3 = 0.f;
      #pragma unroll
      for (int c = 0; c < 8; c++) {
        const float4 kc = kr[c];
        s0 += q[4*c]*kc.x;   s1 += q[4*c+1]*kc.y;
        s2 += q[4*c+2]*kc.z; s3 += q[4*c+3]*kc.w;
      }
      sc[jj] = (s0 + s1) + (s2 + s3);
    }
    float cm = sc[0];
    #pragma unroll
    for (int jj = 1; jj < 8; jj++) cm = fmaxf(cm, sc[jj]);
    if (!__all(cm <= m)) {
      const float nm = fmaxf(m, cm);
      const float e0 = __expf(m - nm);
      sum *= e0;
      #pragma unroll
      for (int d = 0; d < 32; d++) o[d] *= e0;
      m = nm;
    }
    #pragma unroll
    for (int jj = 0; jj < 8; jj++) {
      const int l = l0 + ch*8 + jj;
      const float p = __expf(sc[jj] - m);
      sum += p;
      const float4* vr = (const float4*)(Vb + l*32);
      #pragma unroll
      for (int c = 0; c < 8; c++) {
        const float4 vc = vr[c];
        o[4*c]   += p*vc.x; o[4*c+1] += p*vc.y;
        o[4*c+2] += p*vc.z; o[4*c+3] += p*vc.w;
      }
    }
  }
  if (wave == 3) {  // key 256
    const float4* kr = (const float4*)(Kb + 256*32);
    float s0 = 0.f, s1 = 0.f, s2 = 0.f, s3 = 0.f;
    #pragma unroll
    for (int c = 0; c < 8; c++) {
      const float4 kc = kr[c];
      s0 += q[4*c]*kc.x;   s1 += q[4*c+1]*kc.y;
      s2 += q[4*c+2]*kc.z; s3 += q[4*c+3]*kc.w;
    }
    const float x = (s0 + s1) + (s2 + s3);
    const float nm = fmaxf(m, x);
    const float e0 = __expf(m - nm), p = __expf(x - nm);
    sum = sum*e0 + p;
    const float4* vr = (const float4*)(Vb + 256*32);
    #pragma unroll
    for (int c = 0; c < 8; c++) {
      const float4 vc = vr[c];
      o[4*c]   = o[4*c]*e0   + p*vc.x; o[4*c+1] = o[4*c+1]*e0 + p*vc.y;
      o[4*c+2] = o[4*c+2]*e0 + p*vc.z; o[4*c+3] = o[4*c+3]*e0 + p*vc.w;
    }
    m = nm;
  }
  // stash partials (waves 1..3)
  if (wave > 0) {
    pbuf[wave-1][lane][0] = m;
    pbuf[wave-1][lane][1] = sum;
    #pragma unroll
    for (int c = 0; c < 32; c++) pbuf[wave-1][lane][2+c] = o[c];
  }
  __syncthreads();
  if (wave == 0) {  // merge, publish merged o + inv
    #pragma unroll 1
    for (int w = 0; w < 3; w++) {
      const float mw = pbuf[w][lane][0];
      const float sw = pbuf[w][lane][1];
      const float nm = fmaxf(m, mw);
      const float f = __expf(m - nm), g = __expf(mw - nm);
      sum = sum*f + sw*g;
      #pragma unroll
      for (int c = 0; c < 32; c++) o[c] = o[c]*f + g*pbuf[w][lane][2+c];
      m = nm;
    }
    pbuf[0][lane][0] = 1.f/sum;
    #pragma unroll
    for (int c = 0; c < 32; c++) pbuf[0][lane][2+c] = o[c];
  }
  __syncthreads();
  {  // distributed Wo projection: wave w -> dims [w*8, w*8+8)
    const float inv = pbuf[0][lane][0];
    float oc[32];
    #pragma unroll
    for (int c = 0; c < 32; c++) oc[c] = pbuf[0][lane][2+c];
    const int d0 = wave*8;
    float outv[8];
    #pragma unroll
    for (int dd = 0; dd < 8; dd++) {
      float a = 0.f;
      #pragma unroll
      for (int kd = 0; kd < 32; kd++) a += oc[kd]*wo[kd*32 + d0 + dd];
      outv[dd] = a*inv;
    }
    float4* dst = (float4*)(hob + (size_t)row*32 + d0);
    dst[0] = make_float4(outv[0], outv[1], outv[2], outv[3]);
    dst[1] = make_float4(outv[4], outv[5], outv[6], outv[7]);
  }

  // ---- query row 256: only rg==3 blocks ----
  if (rg == 3) {
    float q2[32];
    {
      const float4* qr = (const float4*)(Qb + 256*32);   // uniform
      #pragma unroll
      for (int c = 0; c < 8; c++) {
        const float4 t4 = qr[c];
        q2[4*c] = t4.x; q2[4*c+1] = t4.y; q2[4*c+2] = t4.z; q2[4*c+3] = t4.w;
      }
    }
    float m2, s2, o2[32];
    {
      const int l = l0 + lane;   // per-lane key (divergent by design)
      const float4* kr = (const float4*)(Kb + l*32);
      const float4* vr = (const float4*)(Vb + l*32);
      float s0 = 0.f, s1 = 0.f, sp = 0.f, s3 = 0.f;
      #pragma unroll
      for (int c = 0; c < 8; c++) {
        const float4 kc = kr[c];
        s0 += q2[4*c]*kc.x;   s1 += q2[4*c+1]*kc.y;
        sp += q2[4*c+2]*kc.z; s3 += q2[4*c+3]*kc.w;
      }
      m2 = (s0 + s1) + (sp + s3);
      s2 = 1.f;
      #pragma unroll
      for (int c = 0; c < 8; c++) {
        const float4 vc = vr[c];
        o2[4*c] = vc.x; o2[4*c+1] = vc.y; o2[4*c+2] = vc.z; o2[4*c+3] = vc.w;
      }
    }
    if (wave == 3 && lane == 0) {  // key 256
      const float4* kr = (const float4*)(Kb + 256*32);
      const float4* vr = (const float4*)(Vb + 256*32);
      float s0 = 0.f, s1 = 0.f, sp = 0.f, s3 = 0.f;
      #pragma unroll
      for (int c = 0; c < 8; c++) {
        const float4 kc = kr[c];
        s0 += q2[4*c]*kc.x;   s1 += q2[4*c+1]*kc.y;
        sp += q2[4*c+2]*kc.z; s3 += q2[4*c+3]*kc.w;
      }
      const float x = (s0 + s1) + (sp + s3);
      const float nm = fmaxf(m2, x);
      const float e0 = __expf(m2 - nm), p = __expf(x - nm);
      s2 = s2*e0 + p;
      #pragma unroll
      for (int c = 0; c < 8; c++) {
        const float4 vc = vr[c];
        o2[4*c]   = o2[4*c]*e0   + p*vc.x; o2[4*c+1] = o2[4*c+1]*e0 + p*vc.y;
        o2[4*c+2] = o2[4*c+2]*e0 + p*vc.z; o2[4*c+3] = o2[4*c+3]*e0 + p*vc.w;
      }
      m2 = nm;
    }
    #pragma unroll 1
    for (int off = 1; off < 64; off <<= 1) {
      const float om = __shfl_xor(m2, off);
      const float os = __shfl_xor(s2, off);
      const float nm = fmaxf(m2, om);
      const float me = __expf(m2 - nm), oe = __expf(om - nm);
      s2 = s2*me + os*oe;
      #pragma unroll
      for (int d = 0; d < 32; d++) o2[d] = o2[d]*me + __shfl_xor(o2[d], off)*oe;
      m2 = nm;
    }
    __syncthreads();   // projection-phase pbuf reads done; safe to reuse
    if (lane == 0) {
      pbuf[0][wave][0] = m2;
      pbuf[0][wave][1] = s2;
      #pragma unroll
      for (int c = 0; c < 32; c++) pbuf[0][wave][2+c] = o2[c];
    }
    __syncthreads();
    if (wave == 0) {
      float mw[4], fw[4];
      #pragma unroll
      for (int w = 0; w < 4; w++) mw[w] = pbuf[0][w][0];
      float M = fmaxf(fmaxf(mw[0], mw[1]), fmaxf(mw[2], mw[3]));
      float S = 0.f;
      #pragma unroll
      for (int w = 0; w < 4; w++) {
        fw[w] = __expf(mw[w] - M);
        S += pbuf[0][w][1]*fw[w];
      }
      const int c = lane & 31;
      float om = 0.f;
      #pragma unroll
      for (int w = 0; w < 4; w++) om += fw[w]*pbuf[0][w][2+c];
      float a = 0.f;
      #pragma unroll
      for (int kd = 0; kd < 32; kd++) a += __shfl(om, kd) * wo[kd*32 + c];
      if (lane < 32) hob[256*32 + c] = a / S;
    }
  }
}

// ---------------------------------------------------------------------------
// grid 514 x 256. Block = 64 rows; wave w computes FF units [w*32, w*32+32);
// all waves stash to LDS, merge redundantly, each writes its 8-float quarter.
__global__ __launch_bounds__(256, 4)
void k_ffln(const float* __restrict__ headout, const float* __restrict__ z,
            const float* __restrict__ bo,
            const float* __restrict__ W_f1, const float* __restrict__ b_f1,
            const float* __restrict__ W_f2, const float* __restrict__ b_f2,
            const float* __restrict__ ln_g, const float* __restrict__ ln_b,
            const float* __restrict__ W_out, const float* __restrict__ b_out,
            float* __restrict__ nf, float* __restrict__ outp, int t) {
  __shared__ float ybuf[4][64][33];
  const int tid = threadIdx.x;
  const int wave = __builtin_amdgcn_readfirstlane(tid >> 6);  // uniform!
  const int lane = tid & 63;
  const int rowid = blockIdx.x*64 + lane;             // 514*64 = 32896 exact
  const int n = rowid / L_SEQ, row = rowid - n*L_SEQ;

  float att[32];
  const float* hob = headout + (size_t)n*4*L_SEQ*32 + (size_t)row*32;
  const float* zr = z + (size_t)rowid*32;
  #pragma unroll
  for (int e = 0; e < 32; e++)
    att[e] = bo[e] + zr[e] + hob[e] + hob[L_SEQ*32 + e]
           + hob[2*L_SEQ*32 + e] + hob[3*L_SEQ*32 + e];
  float mu = 0.f;
  #pragma unroll
  for (int e = 0; e < 32; e++) mu += att[e];
  mu *= (1.f/32.f);
  float var = 0.f;
  #pragma unroll
  for (int e = 0; e < 32; e++) { const float d = att[e]-mu; var += d*d; }
  var *= (1.f/32.f);
  float rstd = 1.f/sqrtf(var + 1e-6f);
  #pragma unroll
  for (int e = 0; e < 32; e++) att[e] = (att[e]-mu)*rstd*ln_g[e] + ln_b[e];

  // FF quarter: j in [wave*32, wave*32+32)
  float y[32];
  #pragma unroll
  for (int e = 0; e < 32; e++) y[e] = 0.f;
  const int j0 = wave*32;
  #pragma unroll 1
  for (int jj = 0; jj < 32; jj++) {
    const int j = j0 + jj;
    float hv = b_f1[j];
    #pragma unroll
    for (int e = 0; e < 32; e++) hv += att[e]*W_f1[e*128 + j];
    hv = fmaxf(hv, 0.f);
    #pragma unroll
    for (int e = 0; e < 32; e++) y[e] += hv*W_f2[j*32 + e];
  }
  #pragma unroll
  for (int e = 0; e < 32; e++) ybuf[wave][lane][e] = y[e];
  __syncthreads();

  #pragma unroll
  for (int e = 0; e < 32; e++)
    y[e] = ybuf[0][lane][e] + ybuf[1][lane][e] + ybuf[2][lane][e]
         + ybuf[3][lane][e] + b_f2[e] + att[e];

  mu = 0.f;
  #pragma unroll
  for (int e = 0; e < 32; e++) mu += y[e];
  mu *= (1.f/32.f);
  var = 0.f;
  #pragma unroll
  for (int e = 0; e < 32; e++) { const float d = y[e]-mu; var += d*d; }
  var *= (1.f/32.f);
  rstd = 1.f/sqrtf(var + 1e-6f);
  float nfv[32];
  #pragma unroll
  for (int e = 0; e < 32; e++) nfv[e] = (y[e]-mu)*rstd*ln_g[e] + ln_b[e];

  float4* nr = (float4*)(nf + (size_t)rowid*32 + wave*8);
  nr[0] = make_float4(nfv[wave*8+0], nfv[wave*8+1], nfv[wave*8+2], nfv[wave*8+3]);
  nr[1] = make_float4(nfv[wave*8+4], nfv[wave*8+5], nfv[wave*8+6], nfv[wave*8+7]);

  if (t == 7 && row == 0 && wave == 0) {
    float a = b_out[0];
    #pragma unroll
    for (int e = 0; e < 32; e++) a += nfv[e]*W_out[e];
    outp[n] = a;
  }
}

// ---------------------------------------------------------------------------
// grid 514 x 256. Block = 64 z-rows; wave w computes mi/mnew columns
// [w*8, w*8+8) (wave-uniform W_mi reads), mnew exchanged via LDS, then z
// e-quarter per wave. Row-0 lanes take the W_in embed path in phase 2.
__global__ __launch_bounds__(256, 4)
void k_memaug(const float* __restrict__ queries, const float* __restrict__ values,
              const float* __restrict__ W_in, const float* __restrict__ b_in,
              const float* __restrict__ W_me, const float* __restrict__ b_me,
              const float* __restrict__ W_mi, const float* __restrict__ b_mi,
              const float* __restrict__ nf, const float* __restrict__ pe,
              float* __restrict__ mem, float* __restrict__ z, int tnext) {
  __shared__ float mbuf[64][33];
  const int tid = threadIdx.x;
  const int wave = __builtin_amdgcn_readfirstlane(tid >> 6);  // uniform!
  const int lane = tid & 63;
  const int rowid = blockIdx.x*64 + lane;             // 514*64 = 32896 exact
  const int n = rowid / L_SEQ, row = rowid - n*L_SEQ;
  const int e0 = wave*8;
  const bool isrow0 = (row == 0);

  if (!isrow0) {
    float xr[32];
    const float4* x4 = (const float4*)(nf + (size_t)rowid*32);
    #pragma unroll
    for (int c = 0; c < 8; c++) {
      const float4 t4 = x4[c];
      xr[4*c] = t4.x; xr[4*c+1] = t4.y; xr[4*c+2] = t4.z; xr[4*c+3] = t4.w;
    }
    float mi0 = b_mi[0];
    #pragma unroll
    for (int e = 0; e < 32; e++) mi0 += xr[e]*W_mi[e*33];
    const float cs = 1.f/(1.f + expf(-mi0));
    const float ga = 1.f/(1.f + expf(cs));    // sigmoid(-cs)
    const float gb = 1.f/(1.f + expf(-cs));   // sigmoid(cs)
    float* mr = mem + ((size_t)n*256 + (row-1))*32 + e0;
    float mnew[8];
    #pragma unroll
    for (int cc = 0; cc < 8; cc++) {
      const int c = e0 + cc;
      float mic = b_mi[1+c];
      #pragma unroll
      for (int e = 0; e < 32; e++) mic += xr[e]*W_mi[e*33 + 1 + c];
      mnew[cc] = ga*mr[cc] + gb*mic;
    }
    ((float4*)mr)[0] = make_float4(mnew[0], mnew[1], mnew[2], mnew[3]);
    ((float4*)mr)[1] = make_float4(mnew[4], mnew[5], mnew[6], mnew[7]);
    #pragma unroll
    for (int cc = 0; cc < 8; cc++) mbuf[lane][e0+cc] = mnew[cc];
  }
  __syncthreads();

  float acc[8];
  if (isrow0) {
    #pragma unroll
    for (int k = 0; k < 8; k++) acc[k] = b_in[e0+k];
    const float* q = queries + n*32;
    const float* v = values + (size_t)((n>>2)*8 + tnext)*32;
    for (int c = 0; c < 32; c++) {
      const float qc = q[c], vc = v[c];
      #pragma unroll
      for (int k = 0; k < 8; k++) acc[k] += qc*W_in[c*32+e0+k] + vc*W_in[(32+c)*32+e0+k];
    }
  } else {
    #pragma unroll
    for (int k = 0; k < 8; k++) acc[k] = b_me[e0+k];
    #pragma unroll 4
    for (int c = 0; c < 32; c++) {
      const float mc = mbuf[lane][c];
      #pragma unroll
      for (int k = 0; k < 8; k++) acc[k] += mc*W_me[c*32+e0+k];
    }
  }
  const float* per = pe + row*32 + e0;
  float4* zr = (float4*)(z + (size_t)rowid*32 + e0);
  zr[0] = make_float4(acc[0]+per[0], acc[1]+per[1], acc[2]+per[2], acc[3]+per[3]);
  zr[1] = make_float4(acc[4]+per[4], acc[5]+per[5], acc[6]+per[6], acc[7]+per[7]);
}

// ---------------------------------------------------------------------------
extern "C" void kernel_launch(void* const* d_in, const int* in_sizes, int n_in,
                              void* d_out, int out_size, void* d_ws, size_t ws_size,
                              hipStream_t stream) {
  const float* queries = (const float*)d_in[0];
  const float* values  = (const float*)d_in[1];
  const float* W_in = (const float*)d_in[2];   const float* b_in = (const float*)d_in[3];
  const float* W_me = (const float*)d_in[4];   const float* b_me = (const float*)d_in[5];
  const float* Wq   = (const float*)d_in[6];   const float* bq   = (const float*)d_in[7];
  const float* Wk   = (const float*)d_in[8];   const float* bk   = (const float*)d_in[9];
  const float* Wv   = (const float*)d_in[10];  const float* bv   = (const float*)d_in[11];
  const float* Wo   = (const float*)d_in[12];  const float* bo   = (const float*)d_in[13];
  const float* W_f1 = (const float*)d_in[14];  const float* b_f1 = (const float*)d_in[15];
  const float* W_f2 = (const float*)d_in[16];  const float* b_f2 = (const float*)d_in[17];
  const float* ln_g = (const float*)d_in[18];  const float* ln_b = (const float*)d_in[19];
  const float* W_out= (const float*)d_in[20];  const float* b_out= (const float*)d_in[21];
  const float* W_mi = (const float*)d_in[22];  const float* b_mi = (const float*)d_in[23];

  float* ws  = (float*)d_ws;
  float* mem = ws;                 // MEM_SZ
  float* z   = mem + MEM_SZ;       // Z_SZ
  float* ho  = z   + Z_SZ;         // HO_SZ
  float* nf  = ho  + HO_SZ;        // NF_SZ
  float* pe  = nf  + NF_SZ;        // PE_SZ
  float* Kg  = pe  + PE_SZ;        // QKV_SZ
  float* Vg  = Kg  + QKV_SZ;       // QKV_SZ
  float* Qg  = Vg  + QKV_SZ;       // QKV_SZ
  float* outp = (float*)d_out;     // 128 floats

  k_init<<<MEM_SZ/256, 256, 0, stream>>>(mem);
  k_pe<<<(L_SEQ*32 + 255)/256, 256, 0, stream>>>(pe);
  k_aug<<<dim3(129, 4), 256, 0, stream>>>(queries, values, W_in, b_in,
                                          W_me, b_me, mem, pe, z, 0);
  for (int t = 0; t < 8; t++) {
    k_proj<<<dim3(512, 3), 256, 0, stream>>>(z, Wq, bq, Wk, bk, Wv, bv, Kg, Vg, Qg);
    k_attn<<<dim3(512, 4), 256, 0, stream>>>(Qg, Kg, Vg, Wo, ho);
    k_ffln<<<514, 256, 0, stream>>>(ho, z, bo, W_f1, b_f1, W_f2, b_f2,
                                    ln_g, ln_b, W_out, b_out, nf, outp, t);
    if (t < 7)
      k_memaug<<<514, 256, 0, stream>>>(queries, values, W_in, b_in, W_me, b_me,
                                        W_mi, b_mi, nf, pe, mem, z, t+1);
  }
}